// Round 3
// baseline (433.563 us; speedup 1.0000x reference)
//
#include <hip/hip_runtime.h>

// RVQ round 5. Round-4 structure, ONE change: pin waves/EU to 4 (min AND max)
// via amdgpu_waves_per_eu(4,4).
//
// Round-4 post-mortem: launch_bounds(256,4) only sets MIN waves/EU; the
// backend's occupancy heuristic kept an 8-waves/EU target (64-VGPR cap) and
// SPILLED the +16-reg xn prefetch instead of relaxing occupancy.
// Signature: VGPR stayed 64, WRITE 203->360 MB (spill stores), FETCH 99->163
// (spill reloads), VALUBusy 25->16, dur 128->204us. Residency is ~2.75
// blocks/CU anyway (LDS/scheduler-capped), so the 8-wave register budget buys
// nothing. Pinning max=4 gives a 512-VGPR budget -> no spill, same residency.
//
// Kept from round 4:
//  - 1-deep token prefetch (xn) issued BEFORE the dots: oldest in the vmcnt
//    FIFO so next-iter's xf wait doesn't drain this iter's stores/atomics;
//    ~600-900cy HBM latency covered by dots/reduce/argmin.
//  - blend ds_reads for all TB tokens grouped after all argmins.
//  - nontemporal stores for out (never re-read; keeps x L3-resident).
//  - 4 wave-uniform code atomics batched onto lanes 0-3.
//
// Reduce-scatter scheme unchanged: lane l owns codeword k=h(l); v[j] holds
// k = j ^ h(l). 8x xor2 + 4x xor1 on DPP, 2x xor4 + 1x xor8 on ds_swizzle,
// then xor16 + shfl32 full sums. h(l) = bit1<<3 | bit0<<2 | bit2<<1 | bit3.
// Argmin: 4 min-steps over k-owner bits, ballot + ctz -> wave-uniform best k.

#define NH 3
#define NK 16
#define DHEAD 256
#define DFULL 768
#define TB 4
#define BLK 256

typedef float f2 __attribute__((ext_vector_type(2)));
typedef float f4 __attribute__((ext_vector_type(4)));

__device__ __forceinline__ float dpp_xor1(float x) {
    return __builtin_bit_cast(float, __builtin_amdgcn_mov_dpp(
        __builtin_bit_cast(int, x), 0xB1, 0xF, 0xF, false));  // quad_perm(1,0,3,2)
}
__device__ __forceinline__ float dpp_xor2(float x) {
    return __builtin_bit_cast(float, __builtin_amdgcn_mov_dpp(
        __builtin_bit_cast(int, x), 0x4E, 0xF, 0xF, false));  // quad_perm(2,3,0,1)
}
__device__ __forceinline__ float swz_xor4(float x) {
    return __builtin_bit_cast(float, __builtin_amdgcn_ds_swizzle(
        __builtin_bit_cast(int, x), 0x101F));
}
__device__ __forceinline__ float swz_xor8(float x) {
    return __builtin_bit_cast(float, __builtin_amdgcn_ds_swizzle(
        __builtin_bit_cast(int, x), 0x201F));
}
__device__ __forceinline__ float swz_xor16(float x) {
    return __builtin_bit_cast(float, __builtin_amdgcn_ds_swizzle(
        __builtin_bit_cast(int, x), 0x401F));
}

__global__ __launch_bounds__(BLK)
__attribute__((amdgpu_waves_per_eu(4, 4)))
void rvq_head_kernel(
    const float* __restrict__ x,
    const float* __restrict__ cb,
    const float* __restrict__ alphap,
    float* __restrict__ out,
    float* __restrict__ codef,
    int tok_per_block)
{
    const int h = blockIdx.y;
    __shared__ float lc[NK * DHEAD];     // 16 KB codebook, head h, stride 256
    __shared__ float lps[BLK];           // norm partials
    __shared__ float lcn[NK];            // codeword squared norms

    const int tid  = threadIdx.x;
    const int lane = tid & 63;
    const int wid  = tid >> 6;

    const int t_base = blockIdx.x * tok_per_block;
    const int t_end  = t_base + tok_per_block;
    const int step   = (BLK / 64) * TB;  // 16 tokens per block-iteration

    const f4* x4 = (const f4*)x;
    f4* out4     = (f4*)out;

    // issue first token loads immediately -- overlaps codebook staging
    int t0 = t_base + wid * TB;
    f4 xf[TB];
    #pragma unroll
    for (int t = 0; t < TB; ++t)
        xf[t] = x4[(size_t)(t0 + t) * (DFULL / 4) + h * 64 + lane];

    // stage head-h codebook (coalesced float4)
    const f4* cb4 = (const f4*)(cb + (size_t)h * NK * DHEAD);
    f4* lc4w = (f4*)lc;
    #pragma unroll
    for (int i = 0; i < 4; ++i) lc4w[tid + i * BLK] = cb4[tid + i * BLK];

    // codeword norm partials: thread i -> row i>>4, 16 dims at (i&15)*16
    {
        const int r = tid >> 4, dd = (tid & 15) * 16;
        const f4* p = (const f4*)(cb + (size_t)h * NK * DHEAD + r * DHEAD + dd);
        float s = 0.f;
        #pragma unroll
        for (int q = 0; q < 4; ++q) {
            f4 c = p[q];
            s += c.x * c.x + c.y * c.y + c.z * c.z + c.w * c.w;
        }
        lps[tid] = s;
    }
    __syncthreads();
    if (tid < NK) {
        float s = 0.f;
        #pragma unroll
        for (int q = 0; q < 16; ++q) s += lps[tid * 16 + q];
        lcn[tid] = s;
    }
    __syncthreads();

    // k owned by this lane after reduce-scatter
    const int hl = (((lane >> 1) & 1) << 3) | ((lane & 1) << 2)
                 | (((lane >> 2) & 1) << 1) | ((lane >> 3) & 1);
    const float cn_l  = lcn[hl];
    const float alpha = alphap[0];
    const float beta  = 1.0f - alpha;
    const float kscale = (float)(1 << (4 * h));

    const f4* lc4 = (const f4*)lc;

    while (t0 < t_end) {
        const int t1 = t0 + step;

        // prefetch next iteration's tokens FIRST: oldest in the vmcnt FIFO
        // (next-iter wait won't drain younger stores/atomics), and the
        // ~600-900cy HBM latency is covered by the dots/reduce/argmin below.
        f4 xn[TB];
        if (t1 < t_end) {
            #pragma unroll
            for (int t = 0; t < TB; ++t)
                xn[t] = x4[(size_t)(t1 + t) * (DFULL / 4) + h * 64 + lane];
        }

        // partial dots: v[t][j] = <x4_lane, c[j^hl]_lane> (packed fp32 fma)
        float v[TB][NK];
        #pragma unroll
        for (int j = 0; j < NK; ++j) {
            f4 c = lc4[((j ^ hl) << 6) | lane];
            #pragma unroll
            for (int t = 0; t < TB; ++t) {
                f2 p = (f2){xf[t].x, xf[t].y} * (f2){c.x, c.y};
                p += (f2){xf[t].z, xf[t].w} * (f2){c.z, c.w};
                v[t][j] = p.x + p.y;
            }
        }

        // recursive-halving reduce-scatter + full sum, then argmin -> bi[t]
        int bi[TB];
        #pragma unroll
        for (int t = 0; t < TB; ++t) {
            #pragma unroll
            for (int j = 0; j < 8; ++j) v[t][j] += dpp_xor2(v[t][j + 8]);
            #pragma unroll
            for (int j = 0; j < 4; ++j) v[t][j] += dpp_xor1(v[t][j + 4]);
            #pragma unroll
            for (int j = 0; j < 2; ++j) v[t][j] += swz_xor4(v[t][j + 2]);
            v[t][0] += swz_xor8(v[t][1]);
            v[t][0] += swz_xor16(v[t][0]);
            v[t][0] += __shfl_xor(v[t][0], 32);

            const float sc = cn_l - 2.0f * v[t][0];
            float m = sc;
            m = fminf(m, dpp_xor1(m));
            m = fminf(m, dpp_xor2(m));
            m = fminf(m, swz_xor4(m));
            m = fminf(m, swz_xor8(m));
            const unsigned long long mask = __ballot(sc == m);
            const int lmin = __builtin_ctzll(mask);
            bi[t] = (((lmin >> 1) & 1) << 3) | ((lmin & 1) << 2)
                  | (((lmin >> 2) & 1) << 1) | ((lmin >> 3) & 1);
        }

        // grouped blend codeword reads (LDS latency pipelined once, not 4x)
        f4 cw[TB];
        #pragma unroll
        for (int t = 0; t < TB; ++t) cw[t] = lc4[(bi[t] << 6) | lane];

        // blend + nontemporal store (out never re-read; keep x L3-resident)
        float bif[TB];
        #pragma unroll
        for (int t = 0; t < TB; ++t) {
            f4 o;
            o.x = alpha * xf[t].x + beta * cw[t].x;
            o.y = alpha * xf[t].y + beta * cw[t].y;
            o.z = alpha * xf[t].z + beta * cw[t].z;
            o.w = alpha * xf[t].w + beta * cw[t].w;
            __builtin_nontemporal_store(o, &out4[(size_t)(t0 + t) * (DFULL / 4)
                                                + h * 64 + lane]);
            bif[t] = (float)bi[t] * kscale;
        }

        // batched code atomics: lanes 0..3 carry the 4 wave-uniform codes
        const float mya = (lane == 0) ? bif[0] : (lane == 1) ? bif[1]
                        : (lane == 2) ? bif[2] : bif[3];
        if (lane < TB) atomicAdd(codef + t0 + lane, mya);

        t0 = t1;
        #pragma unroll
        for (int t = 0; t < TB; ++t) xf[t] = xn[t];
    }
}

extern "C" void kernel_launch(void* const* d_in, const int* in_sizes, int n_in,
                              void* d_out, int out_size, void* d_ws, size_t ws_size,
                              hipStream_t stream) {
    const float* x      = (const float*)d_in[0];
    const float* cb     = (const float*)d_in[1];
    const float* alphap = (const float*)d_in[2];
    const int n_tokens  = in_sizes[0] / DFULL;            // 65536
    float* out   = (float*)d_out;
    float* codef = out + (size_t)n_tokens * DFULL;        // second output

    // code accumulated via fp32 atomicAdd across the 3 head-grids -> zero it
    hipMemsetAsync(codef, 0, (size_t)n_tokens * sizeof(float), stream);

    const int grid_x = 512;
    const int tok_per_block = n_tokens / grid_x;          // 128
    dim3 grid(grid_x, NH);
    rvq_head_kernel<<<grid, BLK, 0, stream>>>(x, cb, alphap, out, codef,
                                              tok_per_block);
}

// Round 4
// 352.247 us; speedup vs baseline: 1.2308x; 1.2308x over previous
//
#include <hip/hip_runtime.h>

// RVQ round 6. Round-2 body (the 128us/dispatch kernel, VGPR=64, no spill)
// + ZERO-VGPR token prefetch: double-buffered per-wave x staging in LDS via
// __builtin_amdgcn_global_load_lds (dest = wave-uniform base + lane*16,
// exactly this access pattern).
//
// Why: rounds 3-5 proved the register-prefetch (xn[4], +16 VGPR) always
// spills -- the allocator pins this kernel at 64 VGPRs (round 5:
// waves_per_eu(4,4) moved SGPR 32->112 but VGPR stayed 64, WRITE stayed
// 360MB spill-inflated). Round 2 fits in 64 only because the scheduler folds
// reduce steps into the dot loop; any extra 16-reg array breaks it.
// global_load_lds costs no destination registers.
//
// Pipeline per wave (no __syncthreads in the loop -- buffers are per-wave):
//   top of iter: s_waitcnt vmcnt(5)   <- waits cur-buffer loads (issued last
//                                        iter) while the 5 younger ops (4 out
//                                        stores + 1 code atomic) stay in
//                                        flight (FIFO vmcnt retire)
//                issue 4 gl_lds into buf^1 for next tokens
//                ds_read xf from buf, compute dots/reduce/argmin/blend/store
// Prologue buffer drained by setup __syncthreads (emits vmcnt(0)).
// Empty asm memory fences pin issue order so the count of 5 is exact.
//
// Reduce-scatter scheme unchanged: lane l owns codeword k=h(l); v[j] holds
// k = j ^ h(l). 8x xor2 + 4x xor1 on DPP, 2x xor4 + 1x xor8 on ds_swizzle,
// then xor16 + shfl32 full sums. h(l) = bit1<<3 | bit0<<2 | bit2<<1 | bit3.
// Argmin: 4 min-steps over k-owner bits, ballot + ctz -> wave-uniform best k.

#define NH 3
#define NK 16
#define DHEAD 256
#define DFULL 768
#define TB 4
#define BLK 256
#define NW (BLK / 64)

typedef float f2 __attribute__((ext_vector_type(2)));
typedef float f4 __attribute__((ext_vector_type(4)));

__device__ __forceinline__ float dpp_xor1(float x) {
    return __builtin_bit_cast(float, __builtin_amdgcn_mov_dpp(
        __builtin_bit_cast(int, x), 0xB1, 0xF, 0xF, false));  // quad_perm(1,0,3,2)
}
__device__ __forceinline__ float dpp_xor2(float x) {
    return __builtin_bit_cast(float, __builtin_amdgcn_mov_dpp(
        __builtin_bit_cast(int, x), 0x4E, 0xF, 0xF, false));  // quad_perm(2,3,0,1)
}
__device__ __forceinline__ float swz_xor4(float x) {
    return __builtin_bit_cast(float, __builtin_amdgcn_ds_swizzle(
        __builtin_bit_cast(int, x), 0x101F));
}
__device__ __forceinline__ float swz_xor8(float x) {
    return __builtin_bit_cast(float, __builtin_amdgcn_ds_swizzle(
        __builtin_bit_cast(int, x), 0x201F));
}
__device__ __forceinline__ float swz_xor16(float x) {
    return __builtin_bit_cast(float, __builtin_amdgcn_ds_swizzle(
        __builtin_bit_cast(int, x), 0x401F));
}

// async global->LDS, 16B/lane, dest = wave-uniform base + lane*16
__device__ __forceinline__ void async_ld16(const float* g, float* l) {
    __builtin_amdgcn_global_load_lds(
        (const __attribute__((address_space(1))) unsigned int*)g,
        (__attribute__((address_space(3))) unsigned int*)l, 16, 0, 0);
}

__global__ __launch_bounds__(BLK, 4) void rvq_head_kernel(
    const float* __restrict__ x,
    const float* __restrict__ cb,
    const float* __restrict__ alphap,
    float* __restrict__ out,
    float* __restrict__ codef,
    int tok_per_block)
{
    const int h = blockIdx.y;
    __shared__ float lc[NK * DHEAD];         // 16 KB codebook, head h
    __shared__ float xbuf[2][NW][TB][256];   // 32 KB: per-wave double buffer
    __shared__ float lps[BLK];               // norm partials
    __shared__ float lcn[NK];                // codeword squared norms

    const int tid  = threadIdx.x;
    const int lane = tid & 63;
    const int wid  = tid >> 6;

    const int t_base = blockIdx.x * tok_per_block;
    const int t_end  = t_base + tok_per_block;
    const int step   = NW * TB;              // 16 tokens per block-iteration

    const f4* x4 = (const f4*)x;
    f4* out4     = (f4*)out;

    // prologue: issue buffer-0 prefetch immediately (drained by syncthreads)
    int t0 = t_base + wid * TB;
    #pragma unroll
    for (int t = 0; t < TB; ++t)
        async_ld16((const float*)&x4[(size_t)(t0 + t) * (DFULL / 4) + h * 64 + lane],
                   &xbuf[0][wid][t][0]);

    // stage head-h codebook (coalesced float4)
    const f4* cb4 = (const f4*)(cb + (size_t)h * NK * DHEAD);
    f4* lc4w = (f4*)lc;
    #pragma unroll
    for (int i = 0; i < 4; ++i) lc4w[tid + i * BLK] = cb4[tid + i * BLK];

    // codeword norm partials: thread i -> row i>>4, 16 dims at (i&15)*16
    {
        const int r = tid >> 4, dd = (tid & 15) * 16;
        const f4* p = (const f4*)(cb + (size_t)h * NK * DHEAD + r * DHEAD + dd);
        float s = 0.f;
        #pragma unroll
        for (int q = 0; q < 4; ++q) {
            f4 c = p[q];
            s += c.x * c.x + c.y * c.y + c.z * c.z + c.w * c.w;
        }
        lps[tid] = s;
    }
    __syncthreads();
    if (tid < NK) {
        float s = 0.f;
        #pragma unroll
        for (int q = 0; q < 16; ++q) s += lps[tid * 16 + q];
        lcn[tid] = s;
    }
    __syncthreads();   // emits s_waitcnt vmcnt(0): buffer 0 is complete here

    // k owned by this lane after reduce-scatter
    const int hl = (((lane >> 1) & 1) << 3) | ((lane & 1) << 2)
                 | (((lane >> 2) & 1) << 1) | ((lane >> 3) & 1);
    const float cn_l  = lcn[hl];
    const float alpha = alphap[0];
    const float beta  = 1.0f - alpha;
    const float kscale = (float)(1 << (4 * h));

    const f4* lc4 = (const f4*)lc;

    int cur = 0;
    while (t0 < t_end) {
        const int t1 = t0 + step;

        // wait for buffer `cur` (loads issued last iter, oldest in FIFO);
        // the 5 younger ops (4 stores + 1 atomic of last iter) may remain.
        asm volatile("s_waitcnt vmcnt(5)" ::: "memory");

        // issue next-buffer prefetch (zero-VGPR async copy)
        if (t1 < t_end) {
            #pragma unroll
            for (int t = 0; t < TB; ++t)
                async_ld16((const float*)&x4[(size_t)(t1 + t) * (DFULL / 4)
                                             + h * 64 + lane],
                           &xbuf[cur ^ 1][wid][t][0]);
        }
        asm volatile("" ::: "memory");  // keep stores/atomic below the loads

        // xf from LDS (per-wave region, conflict-free: lane*16B)
        f4 xf[TB];
        #pragma unroll
        for (int t = 0; t < TB; ++t)
            xf[t] = *(const f4*)&xbuf[cur][wid][t][lane * 4];

        // partial dots: v[t][j] = <x4_lane, c[j^hl]_lane> (packed fp32 fma)
        float v[TB][NK];
        #pragma unroll
        for (int j = 0; j < NK; ++j) {
            f4 c = lc4[((j ^ hl) << 6) | lane];
            #pragma unroll
            for (int t = 0; t < TB; ++t) {
                f2 p = (f2){xf[t].x, xf[t].y} * (f2){c.x, c.y};
                p += (f2){xf[t].z, xf[t].w} * (f2){c.z, c.w};
                v[t][j] = p.x + p.y;
            }
        }

        // recursive-halving reduce-scatter + full sum
        #pragma unroll
        for (int t = 0; t < TB; ++t) {
            #pragma unroll
            for (int j = 0; j < 8; ++j) v[t][j] += dpp_xor2(v[t][j + 8]);
            #pragma unroll
            for (int j = 0; j < 4; ++j) v[t][j] += dpp_xor1(v[t][j + 4]);
            #pragma unroll
            for (int j = 0; j < 2; ++j) v[t][j] += swz_xor4(v[t][j + 2]);
            v[t][0] += swz_xor8(v[t][1]);
            v[t][0] += swz_xor16(v[t][0]);
            v[t][0] += __shfl_xor(v[t][0], 32);
        }

        // score, argmin, blend, store (round-2 form)
        float bif[TB];
        #pragma unroll
        for (int t = 0; t < TB; ++t) {
            const float sc = cn_l - 2.0f * v[t][0];
            float m = sc;
            m = fminf(m, dpp_xor1(m));
            m = fminf(m, dpp_xor2(m));
            m = fminf(m, swz_xor4(m));
            m = fminf(m, swz_xor8(m));
            const unsigned long long mask = __ballot(sc == m);
            const int lmin = __builtin_ctzll(mask);
            const int bi = (((lmin >> 1) & 1) << 3) | ((lmin & 1) << 2)
                         | (((lmin >> 2) & 1) << 1) | ((lmin >> 3) & 1);
            const f4 c = lc4[(bi << 6) | lane];
            f4 o;
            o.x = alpha * xf[t].x + beta * c.x;
            o.y = alpha * xf[t].y + beta * c.y;
            o.z = alpha * xf[t].z + beta * c.z;
            o.w = alpha * xf[t].w + beta * c.w;
            out4[(size_t)(t0 + t) * (DFULL / 4) + h * 64 + lane] = o;
            bif[t] = (float)bi * kscale;
        }

        // batched code atomics: lanes 0..3 carry the 4 wave-uniform codes
        // (exactly 1 VMEM op -> the vmcnt(5) count above stays exact)
        const float mya = (lane == 0) ? bif[0] : (lane == 1) ? bif[1]
                        : (lane == 2) ? bif[2] : bif[3];
        if (lane < TB) atomicAdd(codef + t0 + lane, mya);

        t0 = t1;
        cur ^= 1;
    }
}

extern "C" void kernel_launch(void* const* d_in, const int* in_sizes, int n_in,
                              void* d_out, int out_size, void* d_ws, size_t ws_size,
                              hipStream_t stream) {
    const float* x      = (const float*)d_in[0];
    const float* cb     = (const float*)d_in[1];
    const float* alphap = (const float*)d_in[2];
    const int n_tokens  = in_sizes[0] / DFULL;            // 65536
    float* out   = (float*)d_out;
    float* codef = out + (size_t)n_tokens * DFULL;        // second output

    // code accumulated via fp32 atomicAdd across the 3 head-grids -> zero it
    hipMemsetAsync(codef, 0, (size_t)n_tokens * sizeof(float), stream);

    const int grid_x = 512;
    const int tok_per_block = n_tokens / grid_x;          // 128
    dim3 grid(grid_x, NH);
    rvq_head_kernel<<<grid, BLK, 0, stream>>>(x, cb, alphap, out, codef,
                                              tok_per_block);
}